// Round 5
// baseline (504.927 us; speedup 1.0000x reference)
//
#include <hip/hip_runtime.h>

#define N 8192
#define IN_F 512
#define OUT_F 128
#define SPLITK 8
#define KC 1024
#define LOG2E 1.4426950408889634f
#define LN2 0.6931471805599453f

typedef __attribute__((ext_vector_type(4))) float f32x4;
typedef __attribute__((ext_vector_type(8))) short bf16x8;
typedef __attribute__((ext_vector_type(8))) unsigned short u16x8;
typedef __attribute__((ext_vector_type(4))) int i32x4;

__device__ __forceinline__ short f2bf(float f) {
    union { float f; unsigned u; } c; c.f = f;
    unsigned r = c.u + 0x7FFFu + ((c.u >> 16) & 1u);
    return (short)(r >> 16);
}

__device__ __forceinline__ float exp2fast(float x) {
#if __has_builtin(__builtin_amdgcn_exp2f)
    return __builtin_amdgcn_exp2f(x);
#else
    return __expf(x * LN2);
#endif
}

// ---------------------------------------------------------------- prep: W f32 -> WT bf16 [OUT_F][IN_F]
__global__ __launch_bounds__(256) void prep(const float* __restrict__ W,
                                            short* __restrict__ WT) {
    int idx = blockIdx.x * 256 + threadIdx.x;   // 65536 total
    int n = idx & (OUT_F - 1);
    int k = idx >> 7;
    WT[(size_t)n * IN_F + k] = f2bf(W[idx]);
}

// ---------------------------------------------------------------- gemm_hW: Wh=h@W -> WhT bf16 [OUT_F][N]; fused s,t (x LOG2E)
__global__ __launch_bounds__(256) void gemm_hW(const float* __restrict__ h,
                                               const short* __restrict__ WT,
                                               const float* __restrict__ a,
                                               short* __restrict__ WhT,
                                               float* __restrict__ sOut,
                                               float* __restrict__ tOut) {
    const int tid = threadIdx.x;
    const int wave = tid >> 6, lane = tid & 63;
    const int row16 = lane & 15, kgrp = lane >> 4;
    const int m0 = blockIdx.x * 16;
    const int kbase = wave * 128;

    f32x4 acc[8] = {};
    const float4* hp = (const float4*)(h + (size_t)(m0 + row16) * IN_F + kbase);

#pragma unroll
    for (int kk = 0; kk < 128; kk += 32) {
        float4 u0 = hp[kk / 4 + kgrp * 2];
        float4 u1 = hp[kk / 4 + kgrp * 2 + 1];
        bf16x8 af;
        af[0] = f2bf(u0.x); af[1] = f2bf(u0.y); af[2] = f2bf(u0.z); af[3] = f2bf(u0.w);
        af[4] = f2bf(u1.x); af[5] = f2bf(u1.y); af[6] = f2bf(u1.z); af[7] = f2bf(u1.w);
#pragma unroll
        for (int nt = 0; nt < 8; nt++) {
            bf16x8 bf_ = *(const bf16x8*)(WT + (size_t)(nt * 16 + row16) * IN_F + kbase + kk + kgrp * 8);
            acc[nt] = __builtin_amdgcn_mfma_f32_16x16x32_bf16(af, bf_, acc[nt], 0, 0, 0);
        }
    }

    __shared__ float red[4][16][132];
#pragma unroll
    for (int nt = 0; nt < 8; nt++)
#pragma unroll
        for (int r = 0; r < 4; r++)
            red[wave][kgrp * 4 + r][nt * 16 + row16] = acc[nt][r];
    __syncthreads();

    const int row = tid >> 4, seg = tid & 15;
    float v[8];
#pragma unroll
    for (int e = 0; e < 8; e++) {
        int c = seg * 8 + e;
        v[e] = red[0][row][c] + red[1][row][c] + red[2][row][c] + red[3][row][c];
    }
    float sp = 0.f, tp = 0.f;
#pragma unroll
    for (int e = 0; e < 8; e++) {
        sp += v[e] * a[seg * 8 + e];
        tp += v[e] * a[OUT_F + seg * 8 + e];
    }
    sp += __shfl_xor(sp, 1); tp += __shfl_xor(tp, 1);
    sp += __shfl_xor(sp, 2); tp += __shfl_xor(tp, 2);
    sp += __shfl_xor(sp, 4); tp += __shfl_xor(tp, 4);
    sp += __shfl_xor(sp, 8); tp += __shfl_xor(tp, 8);
    if (seg == 0) {
        sOut[m0 + row] = sp * LOG2E;
        tOut[m0 + row] = tp * LOG2E;
    }
#pragma unroll
    for (int e = 0; e < 8; e++)
        WhT[(size_t)(seg * 8 + e) * N + m0 + row] = f2bf(v[e]);
}

// ---------------------------------------------------------------- attn: ZERO-LDS, ZERO-barrier. B-fragments + t read direct from
// L2-resident WhT/t slices (XCD-pinned via kb = blockIdx.x & 7); adj streamed with distance-2 register pipeline.
// 1-D grid 1024; 256 thr = 4 independent waves; wave = 16M x 128N x 1024K.
__global__ __launch_bounds__(256, 3) void attn(const int* __restrict__ adj,
                                               const short* __restrict__ WhT,
                                               const float* __restrict__ s,
                                               const float* __restrict__ t,
                                               unsigned short* __restrict__ num,
                                               float* __restrict__ lpart) {
    const int tid = threadIdx.x;
    const int wave = tid >> 6, lane = tid & 63;
    const int row16 = lane & 15, kgrp = lane >> 4;
    const int kb = blockIdx.x & 7;
    const int mb = blockIdx.x >> 3;
    const int m0 = mb * 64 + wave * 16;
    const int m  = m0 + row16;
    const int ks = kb * KC;

    const i32x4* ap = (const i32x4*)(adj + (size_t)m * N + ks);
    const int abase = kgrp * 2;

    // adj buffers: ab[sp&1] = superstep sp's 8 ints (2 slices) per lane; distance-2 pipeline.
    i32x4 ab[2][4];
#pragma unroll
    for (int d = 0; d < 2; d++)
#pragma unroll
        for (int hh = 0; hh < 2; hh++) {
            ab[0][d * 2 + hh] = __builtin_nontemporal_load(ap + d * 8 + abase + hh);
            ab[1][d * 2 + hh] = __builtin_nontemporal_load(ap + 16 + d * 8 + abase + hh);
        }

    const float s_m = s[m];

    f32x4 acc[8] = {};
    float lsum = 0.f;

    for (int sp = 0; sp < 16; sp++) {
        const int ss = sp & 1;
        const int k0 = ks + sp * 64;
#pragma unroll
        for (int d = 0; d < 2; d++) {
            const int g = sp * 2 + d;    // slice 0..31
            const i32x4 a0 = ab[ss][d * 2 + 0];
            const i32x4 a1 = ab[ss][d * 2 + 1];

            // B fragments straight from L2-resident WhT (same layout the LDS path produced)
            bf16x8 bfr[8];
            const short* bb = WhT + k0 + d * 32 + kgrp * 8 + (size_t)row16 * N;
#pragma unroll
            for (int ni = 0; ni < 8; ni++)
                bfr[ni] = *(const bf16x8*)(bb + (size_t)(ni * 16) * N);

            // t direct (4 KB slice, L1-resident)
            const float* tp = t + ks + g * 32 + kgrp * 8;
            float4 tA = *(const float4*)tp;
            float4 tB = *(const float4*)(tp + 4);
            float tv[8] = { tA.x, tA.y, tA.z, tA.w, tB.x, tB.y, tB.z, tB.w };

            if (d == 1 && sp + 2 < 16) {
                // adj for sp+2 into the now-dead ab[ss] registers; issued AFTER this
                // iteration's B loads so the B-use wait (newest) leaves these in flight.
                __builtin_amdgcn_sched_barrier(0);
#pragma unroll
                for (int dd = 0; dd < 2; dd++)
#pragma unroll
                    for (int hh = 0; hh < 2; hh++)
                        ab[ss][dd * 2 + hh] =
                            __builtin_nontemporal_load(ap + (sp + 2) * 16 + dd * 8 + abase + hh);
                __builtin_amdgcn_sched_barrier(0);
            }

            bf16x8 af;
            unsigned* au = (unsigned*)&af;
#pragma unroll
            for (int q = 0; q < 4; q++) {
                const int e0 = 2 * q, e1 = 2 * q + 1;
                float x0 = s_m + tv[e0];
                float x1 = s_m + tv[e1];
                x0 = fmaxf(x0, 0.2f * x0);                 // leaky relu
                x1 = fmaxf(x1, 0.2f * x1);
                unsigned u0 = __float_as_uint(exp2fast(x0)) & 0xFFFF0000u;
                unsigned u1 = __float_as_uint(exp2fast(x1)) & 0xFFFF0000u;
                const int av0 = (e0 < 4) ? a0[e0] : a1[e0 - 4];
                const int av1 = (e1 < 4) ? a0[e1] : a1[e1 - 4];
                u0 = av0 > 0 ? u0 : 0u;                    // adj mask
                u1 = av1 > 0 ? u1 : 0u;
                lsum += __uint_as_float(u0);               // consistent with numerator
                lsum += __uint_as_float(u1);
                au[q] = (u0 >> 16) | u1;
            }
#pragma unroll
            for (int ni = 0; ni < 8; ni++)
                acc[ni] = __builtin_amdgcn_mfma_f32_16x16x32_bf16(af, bfr[ni], acc[ni], 0, 0, 0);
        }
    }

    // row sum across kgrp lanes
    {
        float v = lsum;
        v += __shfl_xor(v, 16);
        v += __shfl_xor(v, 32);
        if (kgrp == 0) lpart[(size_t)kb * N + m] = v;
    }

    // partial numerator, bf16: C layout row = kgrp*4+r (m within 16), col = ni*16+row16
    unsigned short* np_ = num + ((size_t)kb * N + m0) * OUT_F;
#pragma unroll
    for (int ni = 0; ni < 8; ni++) {
        int n = ni * 16 + row16;
#pragma unroll
        for (int r = 0; r < 4; r++)
            np_[(size_t)(kgrp * 4 + r) * OUT_F + n] = (unsigned short)f2bf(acc[ni][r]);
    }
}

// ---------------------------------------------------------------- finalize: reduce bf16 splits, /l, +rnd, elu
__global__ __launch_bounds__(256) void finalize(const unsigned short* __restrict__ num,
                                                const float* __restrict__ lpart,
                                                const float* __restrict__ rnd,
                                                float* __restrict__ out) {
    int idx = blockIdx.x * 256 + threadIdx.x;   // one thread = 8 outputs
    int m = idx >> 4;
    int c = (idx & 15) * 8;
    size_t g = (size_t)m * OUT_F + c;

    float nm[8] = {};
#pragma unroll
    for (int bk = 0; bk < SPLITK; bk++) {
        u16x8 v = *(const u16x8*)(num + (size_t)bk * N * OUT_F + g);
#pragma unroll
        for (int e = 0; e < 8; e++) nm[e] += __uint_as_float((unsigned)v[e] << 16);
    }
    float l = 0.f;
#pragma unroll
    for (int bk = 0; bk < SPLITK; bk++) l += lpart[(size_t)bk * N + m];
    float inv = 1.f / fmaxf(l, 1e-30f);

    float4 r0 = *(const float4*)(rnd + g);
    float4 r1 = *(const float4*)(rnd + g + 4);
    float rv[8] = { r0.x, r0.y, r0.z, r0.w, r1.x, r1.y, r1.z, r1.w };
    float ov[8];
#pragma unroll
    for (int e = 0; e < 8; e++) {
        float x = (nm[e] * inv + rv[e]) * 1e-5f;
        ov[e] = x > 0.f ? x : __expf(x) - 1.f;
    }
    *(float4*)(out + g)     = make_float4(ov[0], ov[1], ov[2], ov[3]);
    *(float4*)(out + g + 4) = make_float4(ov[4], ov[5], ov[6], ov[7]);
}

extern "C" void kernel_launch(void* const* d_in, const int* in_sizes, int n_in,
                              void* d_out, int out_size, void* d_ws, size_t ws_size,
                              hipStream_t stream) {
    const float* h   = (const float*)d_in[0];
    const int*   adj = (const int*)d_in[1];
    const float* W   = (const float*)d_in[2];
    const float* a   = (const float*)d_in[3];
    const float* rnd = (const float*)d_in[4];
    float* out = (float*)d_out;

    char* w = (char*)d_ws;
    short* WT    = (short*)(w);                            // 131072
    short* WhT   = (short*)(w + 131072);                   // 2097152 -> 2228224
    float* sv    = (float*)(w + 2228224);                  // 32768   -> 2260992
    float* tv    = (float*)(w + 2260992);                  // 32768   -> 2293760
    float* lpart = (float*)(w + 2293760);                  // 262144  -> 2555904
    unsigned short* num  = (unsigned short*)(w + 2555904); // 16777216 -> 19333120 (~19 MB)

    prep    <<<256, 256, 0, stream>>>(W, WT);
    gemm_hW <<<512, 256, 0, stream>>>(h, WT, a, WhT, sv, tv);
    attn    <<<1024, 256, 0, stream>>>(adj, WhT, sv, tv, num, lpart);
    finalize<<<512, 256, 0, stream>>>(num, lpart, rnd, out);
}

// Round 6
// 458.302 us; speedup vs baseline: 1.1017x; 1.1017x over previous
//
#include <hip/hip_runtime.h>

#define N 8192
#define IN_F 512
#define OUT_F 128
#define SPLITK 8
#define KC 1024
#define LOG2E 1.4426950408889634f
#define LN2 0.6931471805599453f

typedef __attribute__((ext_vector_type(4))) float f32x4;
typedef __attribute__((ext_vector_type(8))) short bf16x8;
typedef __attribute__((ext_vector_type(8))) unsigned short u16x8;
typedef __attribute__((ext_vector_type(4))) int i32x4;

__device__ __forceinline__ short f2bf(float f) {
    union { float f; unsigned u; } c; c.f = f;
    unsigned r = c.u + 0x7FFFu + ((c.u >> 16) & 1u);
    return (short)(r >> 16);
}

__device__ __forceinline__ float exp2fast(float x) {
#if __has_builtin(__builtin_amdgcn_exp2f)
    return __builtin_amdgcn_exp2f(x);
#else
    return __expf(x * LN2);
#endif
}

// ---------------------------------------------------------------- prep: W f32 -> WT bf16 [OUT_F][IN_F]
__global__ __launch_bounds__(256) void prep(const float* __restrict__ W,
                                            short* __restrict__ WT) {
    int idx = blockIdx.x * 256 + threadIdx.x;   // 65536 total
    int n = idx & (OUT_F - 1);
    int k = idx >> 7;
    WT[(size_t)n * IN_F + k] = f2bf(W[idx]);
}

// ---------------------------------------------------------------- gemm_hW: Wh=h@W -> Bpack (MFMA-fragment-packed, see attn);
// fused s,t (x LOG2E). Bpack[((G*8+ni)*64 + lane)*8 + e] = bf16(Wh[k][n]),
// G = k>>5, lane = ((k>>3)&3)*16 + (n&15), e = k&7, ni = n>>4.
__global__ __launch_bounds__(256) void gemm_hW(const float* __restrict__ h,
                                               const short* __restrict__ WT,
                                               const float* __restrict__ a,
                                               short* __restrict__ Bpack,
                                               float* __restrict__ sOut,
                                               float* __restrict__ tOut) {
    const int tid = threadIdx.x;
    const int wave = tid >> 6, lane = tid & 63;
    const int row16 = lane & 15, kgrp = lane >> 4;
    const int m0 = blockIdx.x * 16;
    const int kbase = wave * 128;

    f32x4 acc[8] = {};
    const float4* hp = (const float4*)(h + (size_t)(m0 + row16) * IN_F + kbase);

#pragma unroll
    for (int kk = 0; kk < 128; kk += 32) {
        float4 u0 = hp[kk / 4 + kgrp * 2];
        float4 u1 = hp[kk / 4 + kgrp * 2 + 1];
        bf16x8 af;
        af[0] = f2bf(u0.x); af[1] = f2bf(u0.y); af[2] = f2bf(u0.z); af[3] = f2bf(u0.w);
        af[4] = f2bf(u1.x); af[5] = f2bf(u1.y); af[6] = f2bf(u1.z); af[7] = f2bf(u1.w);
#pragma unroll
        for (int nt = 0; nt < 8; nt++) {
            bf16x8 bf_ = *(const bf16x8*)(WT + (size_t)(nt * 16 + row16) * IN_F + kbase + kk + kgrp * 8);
            acc[nt] = __builtin_amdgcn_mfma_f32_16x16x32_bf16(af, bf_, acc[nt], 0, 0, 0);
        }
    }

    __shared__ float red[4][16][132];
#pragma unroll
    for (int nt = 0; nt < 8; nt++)
#pragma unroll
        for (int r = 0; r < 4; r++)
            red[wave][kgrp * 4 + r][nt * 16 + row16] = acc[nt][r];
    __syncthreads();

    const int row = tid >> 4, seg = tid & 15;
    float v[8];
#pragma unroll
    for (int e = 0; e < 8; e++) {
        int c = seg * 8 + e;
        v[e] = red[0][row][c] + red[1][row][c] + red[2][row][c] + red[3][row][c];
    }
    float sp = 0.f, tp = 0.f;
#pragma unroll
    for (int e = 0; e < 8; e++) {
        sp += v[e] * a[seg * 8 + e];
        tp += v[e] * a[OUT_F + seg * 8 + e];
    }
    sp += __shfl_xor(sp, 1); tp += __shfl_xor(tp, 1);
    sp += __shfl_xor(sp, 2); tp += __shfl_xor(tp, 2);
    sp += __shfl_xor(sp, 4); tp += __shfl_xor(tp, 4);
    sp += __shfl_xor(sp, 8); tp += __shfl_xor(tp, 8);
    if (seg == 0) {
        sOut[m0 + row] = sp * LOG2E;
        tOut[m0 + row] = tp * LOG2E;
    }

    // Bpack scatter: v[e] is Wh[k=m0+row][n=seg*8+e]
    {
        const int k = m0 + row;
        const int G = k >> 5;
        const int ksub = (k >> 3) & 3;
        const int elem = k & 7;
        const int ni = seg >> 1;
        short* bp = Bpack + ((size_t)(G * 8 + ni) * 64 + ksub * 16 + (seg & 1) * 8) * 8 + elem;
#pragma unroll
        for (int e = 0; e < 8; e++)
            bp[e * 8] = f2bf(v[e]);
    }
}

// ---------------------------------------------------------------- attn: ZERO-LDS, ZERO-barrier; B from fragment-packed Bpack
// (1 KB fully-coalesced load per instruction, XCD-L2-resident via kb pinning); adj distance-2 register pipeline.
// 1-D grid 1024; kb = blockIdx.x & 7; 256 thr = 4 independent waves; wave = 16M x 128N x 1024K.
__global__ __launch_bounds__(256, 3) void attn(const int* __restrict__ adj,
                                               const short* __restrict__ Bpack,
                                               const float* __restrict__ s,
                                               const float* __restrict__ t,
                                               unsigned short* __restrict__ num,
                                               float* __restrict__ lpart) {
    const int tid = threadIdx.x;
    const int wave = tid >> 6, lane = tid & 63;
    const int row16 = lane & 15, kgrp = lane >> 4;
    const int kb = blockIdx.x & 7;
    const int mb = blockIdx.x >> 3;
    const int m0 = mb * 64 + wave * 16;
    const int m  = m0 + row16;
    const int ks = kb * KC;

    const i32x4* ap = (const i32x4*)(adj + (size_t)m * N + ks);
    const int abase = kgrp * 2;

    // adj buffers: ab[sp&1] = superstep sp's 8 ints (2 slices) per lane; distance-2 pipeline.
    i32x4 ab[2][4];
#pragma unroll
    for (int d = 0; d < 2; d++)
#pragma unroll
        for (int hh = 0; hh < 2; hh++) {
            ab[0][d * 2 + hh] = __builtin_nontemporal_load(ap + d * 8 + abase + hh);
            ab[1][d * 2 + hh] = __builtin_nontemporal_load(ap + 16 + d * 8 + abase + hh);
        }

    const float s_m = s[m];

    f32x4 acc[8] = {};
    float lsum = 0.f;

    for (int sp = 0; sp < 16; sp++) {
        const int ss = sp & 1;
#pragma unroll
        for (int d = 0; d < 2; d++) {
            const int g = sp * 2 + d;    // slice 0..31 within this kb
            const i32x4 a0 = ab[ss][d * 2 + 0];
            const i32x4 a1 = ab[ss][d * 2 + 1];

            // B fragments from Bpack: contiguous 1 KB per instruction (lane-indexed)
            bf16x8 bfr[8];
            const short* bb = Bpack + ((size_t)(kb * 32 + g) * 8 * 64 + lane) * 8;
#pragma unroll
            for (int ni = 0; ni < 8; ni++)
                bfr[ni] = *(const bf16x8*)(bb + (size_t)ni * 512);

            // t direct (4 KB slice, cache-resident)
            const float* tp = t + ks + g * 32 + kgrp * 8;
            float4 tA = *(const float4*)tp;
            float4 tB = *(const float4*)(tp + 4);
            float tv[8] = { tA.x, tA.y, tA.z, tA.w, tB.x, tB.y, tB.z, tB.w };

            if (d == 1 && sp + 2 < 16) {
                // adj for sp+2 into the now-dead ab[ss] registers
                __builtin_amdgcn_sched_barrier(0);
#pragma unroll
                for (int dd = 0; dd < 2; dd++)
#pragma unroll
                    for (int hh = 0; hh < 2; hh++)
                        ab[ss][dd * 2 + hh] =
                            __builtin_nontemporal_load(ap + (sp + 2) * 16 + dd * 8 + abase + hh);
                __builtin_amdgcn_sched_barrier(0);
            }

            bf16x8 af;
            unsigned* au = (unsigned*)&af;
#pragma unroll
            for (int q = 0; q < 4; q++) {
                const int e0 = 2 * q, e1 = 2 * q + 1;
                float x0 = s_m + tv[e0];
                float x1 = s_m + tv[e1];
                x0 = fmaxf(x0, 0.2f * x0);                 // leaky relu
                x1 = fmaxf(x1, 0.2f * x1);
                unsigned u0 = __float_as_uint(exp2fast(x0)) & 0xFFFF0000u;
                unsigned u1 = __float_as_uint(exp2fast(x1)) & 0xFFFF0000u;
                const int av0 = (e0 < 4) ? a0[e0] : a1[e0 - 4];
                const int av1 = (e1 < 4) ? a0[e1] : a1[e1 - 4];
                u0 = av0 > 0 ? u0 : 0u;                    // adj mask
                u1 = av1 > 0 ? u1 : 0u;
                lsum += __uint_as_float(u0);               // consistent with numerator
                lsum += __uint_as_float(u1);
                au[q] = (u0 >> 16) | u1;
            }
#pragma unroll
            for (int ni = 0; ni < 8; ni++)
                acc[ni] = __builtin_amdgcn_mfma_f32_16x16x32_bf16(af, bfr[ni], acc[ni], 0, 0, 0);
        }
    }

    // row sum across kgrp lanes
    {
        float v = lsum;
        v += __shfl_xor(v, 16);
        v += __shfl_xor(v, 32);
        if (kgrp == 0) lpart[(size_t)kb * N + m] = v;
    }

    // partial numerator, bf16: C layout row = kgrp*4+r (m within 16), col = ni*16+row16
    unsigned short* np_ = num + ((size_t)kb * N + m0) * OUT_F;
#pragma unroll
    for (int ni = 0; ni < 8; ni++) {
        int n = ni * 16 + row16;
#pragma unroll
        for (int r = 0; r < 4; r++)
            np_[(size_t)(kgrp * 4 + r) * OUT_F + n] = (unsigned short)f2bf(acc[ni][r]);
    }
}

// ---------------------------------------------------------------- finalize: reduce bf16 splits, /l, +rnd, elu
__global__ __launch_bounds__(256) void finalize(const unsigned short* __restrict__ num,
                                                const float* __restrict__ lpart,
                                                const float* __restrict__ rnd,
                                                float* __restrict__ out) {
    int idx = blockIdx.x * 256 + threadIdx.x;   // one thread = 8 outputs
    int m = idx >> 4;
    int c = (idx & 15) * 8;
    size_t g = (size_t)m * OUT_F + c;

    float nm[8] = {};
#pragma unroll
    for (int bk = 0; bk < SPLITK; bk++) {
        u16x8 v = *(const u16x8*)(num + (size_t)bk * N * OUT_F + g);
#pragma unroll
        for (int e = 0; e < 8; e++) nm[e] += __uint_as_float((unsigned)v[e] << 16);
    }
    float l = 0.f;
#pragma unroll
    for (int bk = 0; bk < SPLITK; bk++) l += lpart[(size_t)bk * N + m];
    float inv = 1.f / fmaxf(l, 1e-30f);

    float4 r0 = *(const float4*)(rnd + g);
    float4 r1 = *(const float4*)(rnd + g + 4);
    float rv[8] = { r0.x, r0.y, r0.z, r0.w, r1.x, r1.y, r1.z, r1.w };
    float ov[8];
#pragma unroll
    for (int e = 0; e < 8; e++) {
        float x = (nm[e] * inv + rv[e]) * 1e-5f;
        ov[e] = x > 0.f ? x : __expf(x) - 1.f;
    }
    *(float4*)(out + g)     = make_float4(ov[0], ov[1], ov[2], ov[3]);
    *(float4*)(out + g + 4) = make_float4(ov[4], ov[5], ov[6], ov[7]);
}

extern "C" void kernel_launch(void* const* d_in, const int* in_sizes, int n_in,
                              void* d_out, int out_size, void* d_ws, size_t ws_size,
                              hipStream_t stream) {
    const float* h   = (const float*)d_in[0];
    const int*   adj = (const int*)d_in[1];
    const float* W   = (const float*)d_in[2];
    const float* a   = (const float*)d_in[3];
    const float* rnd = (const float*)d_in[4];
    float* out = (float*)d_out;

    char* w = (char*)d_ws;
    short* WT    = (short*)(w);                            // 131072
    short* Bpack = (short*)(w + 131072);                   // 2097152 -> 2228224
    float* sv    = (float*)(w + 2228224);                  // 32768   -> 2260992
    float* tv    = (float*)(w + 2260992);                  // 32768   -> 2293760
    float* lpart = (float*)(w + 2293760);                  // 262144  -> 2555904
    unsigned short* num  = (unsigned short*)(w + 2555904); // 16777216 -> 19333120 (~19 MB)

    prep    <<<256, 256, 0, stream>>>(W, WT);
    gemm_hW <<<512, 256, 0, stream>>>(h, WT, a, Bpack, sv, tv);
    attn    <<<1024, 256, 0, stream>>>(adj, Bpack, sv, tv, num, lpart);
    finalize<<<512, 256, 0, stream>>>(num, lpart, rnd, out);
}

// Round 7
// 443.880 us; speedup vs baseline: 1.1375x; 1.0325x over previous
//
#include <hip/hip_runtime.h>

#define N 8192
#define IN_F 512
#define OUT_F 128
#define SPLITK 8
#define KC 1024
#define LOG2E 1.4426950408889634f
#define LN2 0.6931471805599453f

typedef __attribute__((ext_vector_type(4))) float f32x4;
typedef __attribute__((ext_vector_type(8))) short bf16x8;
typedef __attribute__((ext_vector_type(8))) unsigned short u16x8;
typedef __attribute__((ext_vector_type(4))) int i32x4;

__device__ __forceinline__ short f2bf(float f) {
    union { float f; unsigned u; } c; c.f = f;
    unsigned r = c.u + 0x7FFFu + ((c.u >> 16) & 1u);
    return (short)(r >> 16);
}

__device__ __forceinline__ float exp2fast(float x) {
#if __has_builtin(__builtin_amdgcn_exp2f)
    return __builtin_amdgcn_exp2f(x);
#else
    return __expf(x * LN2);
#endif
}

__device__ __forceinline__ void load_lds16(const void* g, void* l) {
    __builtin_amdgcn_global_load_lds((const __attribute__((address_space(1))) unsigned*)g,
                                     (__attribute__((address_space(3))) unsigned*)l,
                                     16, 0, 0);
}

// ---------------------------------------------------------------- prep: W f32 -> WT bf16 [OUT_F][IN_F]
__global__ __launch_bounds__(256) void prep(const float* __restrict__ W,
                                            short* __restrict__ WT) {
    int idx = blockIdx.x * 256 + threadIdx.x;   // 65536 total
    int n = idx & (OUT_F - 1);
    int k = idx >> 7;
    WT[(size_t)n * IN_F + k] = f2bf(W[idx]);
}

// ---------------------------------------------------------------- gemm_hW: Wh=h@W -> WhT bf16 [OUT_F][N]; fused s,t (x LOG2E)
__global__ __launch_bounds__(256) void gemm_hW(const float* __restrict__ h,
                                               const short* __restrict__ WT,
                                               const float* __restrict__ a,
                                               short* __restrict__ WhT,
                                               float* __restrict__ sOut,
                                               float* __restrict__ tOut) {
    const int tid = threadIdx.x;
    const int wave = tid >> 6, lane = tid & 63;
    const int row16 = lane & 15, kgrp = lane >> 4;
    const int m0 = blockIdx.x * 16;
    const int kbase = wave * 128;

    f32x4 acc[8] = {};
    const float4* hp = (const float4*)(h + (size_t)(m0 + row16) * IN_F + kbase);

#pragma unroll
    for (int kk = 0; kk < 128; kk += 32) {
        float4 u0 = hp[kk / 4 + kgrp * 2];
        float4 u1 = hp[kk / 4 + kgrp * 2 + 1];
        bf16x8 af;
        af[0] = f2bf(u0.x); af[1] = f2bf(u0.y); af[2] = f2bf(u0.z); af[3] = f2bf(u0.w);
        af[4] = f2bf(u1.x); af[5] = f2bf(u1.y); af[6] = f2bf(u1.z); af[7] = f2bf(u1.w);
#pragma unroll
        for (int nt = 0; nt < 8; nt++) {
            bf16x8 bf_ = *(const bf16x8*)(WT + (size_t)(nt * 16 + row16) * IN_F + kbase + kk + kgrp * 8);
            acc[nt] = __builtin_amdgcn_mfma_f32_16x16x32_bf16(af, bf_, acc[nt], 0, 0, 0);
        }
    }

    __shared__ float red[4][16][132];
#pragma unroll
    for (int nt = 0; nt < 8; nt++)
#pragma unroll
        for (int r = 0; r < 4; r++)
            red[wave][kgrp * 4 + r][nt * 16 + row16] = acc[nt][r];
    __syncthreads();

    const int row = tid >> 4, seg = tid & 15;
    float v[8];
#pragma unroll
    for (int e = 0; e < 8; e++) {
        int c = seg * 8 + e;
        v[e] = red[0][row][c] + red[1][row][c] + red[2][row][c] + red[3][row][c];
    }
    float sp = 0.f, tp = 0.f;
#pragma unroll
    for (int e = 0; e < 8; e++) {
        sp += v[e] * a[seg * 8 + e];
        tp += v[e] * a[OUT_F + seg * 8 + e];
    }
    sp += __shfl_xor(sp, 1); tp += __shfl_xor(tp, 1);
    sp += __shfl_xor(sp, 2); tp += __shfl_xor(tp, 2);
    sp += __shfl_xor(sp, 4); tp += __shfl_xor(tp, 4);
    sp += __shfl_xor(sp, 8); tp += __shfl_xor(tp, 8);
    if (seg == 0) {
        sOut[m0 + row] = sp * LOG2E;
        tOut[m0 + row] = tp * LOG2E;
    }
#pragma unroll
    for (int e = 0; e < 8; e++)
        WhT[(size_t)(seg * 8 + e) * N + m0 + row] = f2bf(v[e]);
}

// ---------------------------------------------------------------- attn: producer/consumer wave specialization.
// 512 thr: waves 0-3 = consumers (16M x 128N each, LDS-staged B, mask from LDS ring);
//          waves 4-7 = producers (stream adj -> u16 bitmask -> 4-slot LDS ring, 2 ss ahead).
// Role-split barriers: producers NEVER drain vmcnt (their HBM pipeline spans barriers);
// consumers drain only their 4 stage loads. 1-D grid 1024; kb = blockIdx.x & 7 XCD-pins the K-slice.
__global__ __launch_bounds__(512, 4) void attn(const int* __restrict__ adj,
                                               const short* __restrict__ WhT,
                                               const float* __restrict__ s,
                                               const float* __restrict__ t,
                                               unsigned short* __restrict__ num,
                                               float* __restrict__ lpart) {
    const int tid = threadIdx.x;
    const int wave = tid >> 6, lane = tid & 63;
    const int kb = blockIdx.x & 7;
    const int mb = blockIdx.x >> 3;
    const int m0blk = mb * 64;
    const int ks = kb * KC;

    __shared__ short Bs[2][2][128 * 32];        // 32 KB: [parity][slice][n*32+k]
    __shared__ float tl[KC];                    // 4 KB
    __shared__ unsigned short maskL[4][64 * 4]; // 2 KB ring: [slot][row*4 + seg16]

    if (wave < 4) {
        // ------------------------------ consumers ------------------------------
        const int row16 = lane & 15, kgrp = lane >> 4;
        const int m0 = m0blk + wave * 16;
        const int m = m0 + row16;

        for (int i = tid; i < KC; i += 256) tl[i] = t[ks + i];
        const float s_m = s[m];

        auto stageB = [&](int sup, int par) {
            const int k0 = ks + sup * 64;
#pragma unroll
            for (int dd = 0; dd < 2; dd++)
#pragma unroll
                for (int q = 0; q < 2; q++) {
                    int nrow = wave * 32 + q * 16 + (lane >> 2);
                    const short* gg = WhT + (size_t)nrow * N + k0 + dd * 32 + (lane & 3) * 8;
                    load_lds16(gg, &Bs[par][dd][(wave * 32 + q * 16) * 32]);
                }
        };

        f32x4 acc[8] = {};
        float lsum = 0.f;

        stageB(0, 0);
        asm volatile("s_waitcnt vmcnt(0) lgkmcnt(0)\n\ts_barrier" ::: "memory");

        for (int sp = 0; sp < 16; sp++) {
            const int par = sp & 1;
            if (sp + 1 < 16) stageB(sp + 1, par ^ 1);

            // row bitmask for this superstep (produced 2 ss ago, double-barrier'd)
            const unsigned long long mk =
                ((const unsigned long long*)&maskL[sp & 3][0])[wave * 16 + row16];

#pragma unroll
            for (int d = 0; d < 2; d++) {
                const int g = sp * 2 + d;    // slice 0..31
                const unsigned mbyte = (unsigned)((mk >> (d * 32 + kgrp * 8)) & 0xFFull);

                const float* tp = tl + g * 32 + kgrp * 8;
                float4 tA = *(const float4*)tp;
                float4 tB = *(const float4*)(tp + 4);
                float tv[8] = { tA.x, tA.y, tA.z, tA.w, tB.x, tB.y, tB.z, tB.w };

                bf16x8 bfr[8];
                const short* base = &Bs[par][d][0];
#pragma unroll
                for (int ni = 0; ni < 8; ni++)
                    bfr[ni] = *(const bf16x8*)(base + (ni * 16 + row16) * 32 + kgrp * 8);

                bf16x8 af;
                unsigned* au = (unsigned*)&af;
#pragma unroll
                for (int q = 0; q < 4; q++) {
                    const int e0 = 2 * q, e1 = 2 * q + 1;
                    float x0 = s_m + tv[e0];
                    float x1 = s_m + tv[e1];
                    x0 = fmaxf(x0, 0.2f * x0);                 // leaky relu
                    x1 = fmaxf(x1, 0.2f * x1);
                    unsigned u0 = __float_as_uint(exp2fast(x0)) & 0xFFFF0000u;
                    unsigned u1 = __float_as_uint(exp2fast(x1)) & 0xFFFF0000u;
                    u0 = ((mbyte >> e0) & 1u) ? u0 : 0u;       // adj mask
                    u1 = ((mbyte >> e1) & 1u) ? u1 : 0u;
                    lsum += __uint_as_float(u0);               // consistent with numerator
                    lsum += __uint_as_float(u1);
                    au[q] = (u0 >> 16) | u1;
                }
#pragma unroll
                for (int ni = 0; ni < 8; ni++)
                    acc[ni] = __builtin_amdgcn_mfma_f32_16x16x32_bf16(af, bfr[ni], acc[ni], 0, 0, 0);
            }
            // drain ONLY this wave's 4 stage loads; producer loads unaffected
            asm volatile("s_waitcnt vmcnt(0)\n\ts_barrier" ::: "memory");
        }

        // row sum across kgrp lanes
        {
            float v = lsum;
            v += __shfl_xor(v, 16);
            v += __shfl_xor(v, 32);
            if (kgrp == 0) lpart[(size_t)kb * N + m] = v;
        }

        // partial numerator, bf16: C layout row = kgrp*4+r (m within 16), col = ni*16+row16
        unsigned short* np_ = num + ((size_t)kb * N + m0) * OUT_F;
#pragma unroll
        for (int ni = 0; ni < 8; ni++) {
            int n = ni * 16 + row16;
#pragma unroll
            for (int r = 0; r < 4; r++)
                np_[(size_t)(kgrp * 4 + r) * OUT_F + n] = (unsigned short)f2bf(acc[ni][r]);
        }
    } else {
        // ------------------------------ producers ------------------------------
        // lane -> (row, 16-wide k segment): prow = (wave-4)*16 + lane>>2, seg = lane&3.
        // Per ss: 4x dwordx4 = 16 adj ints -> u16 bitmask -> maskL[slot][prow*4+seg].
        const int pw = wave - 4;
        const int prow = pw * 16 + (lane >> 2);
        const int seg = lane & 3;
        const i32x4* bp4 = (const i32x4*)(adj + (size_t)(m0blk + prow) * N + ks + seg * 16);

        i32x4 pb[2][4];
        auto ldss = [&](int ssv, int wh) {
#pragma unroll
            for (int q = 0; q < 4; q++)
                pb[wh][q] = __builtin_nontemporal_load(bp4 + ssv * 16 + q);
        };
        auto packw = [&](int wh, int slot) {
            unsigned u = 0;
#pragma unroll
            for (int q = 0; q < 4; q++)
#pragma unroll
                for (int j = 0; j < 4; j++)
                    u |= (unsigned)(pb[wh][q][j] > 0) << (q * 4 + j);
            maskL[slot][prow * 4 + seg] = (unsigned short)u;
        };

        // prologue: slots 0,1 filled; ss2,ss3 in flight
        ldss(0, 0); ldss(1, 1);
        packw(0, 0); packw(1, 1);
        ldss(2, 0); ldss(3, 1);
        asm volatile("s_waitcnt lgkmcnt(0)\n\ts_barrier" ::: "memory");

        for (int sp = 0; sp < 16; sp++) {
            const int wh = sp & 1;
            if (sp + 2 < 16) packw(wh, (sp + 2) & 3);   // waits own vmcnt for ss sp+2 data
            if (sp + 4 < 16) ldss(sp + 4, wh);          // refill freed regs
            asm volatile("s_waitcnt lgkmcnt(0)\n\ts_barrier" ::: "memory");
        }
    }
}

// ---------------------------------------------------------------- finalize: reduce bf16 splits, /l, +rnd, elu
__global__ __launch_bounds__(256) void finalize(const unsigned short* __restrict__ num,
                                                const float* __restrict__ lpart,
                                                const float* __restrict__ rnd,
                                                float* __restrict__ out) {
    int idx = blockIdx.x * 256 + threadIdx.x;   // one thread = 8 outputs
    int m = idx >> 4;
    int c = (idx & 15) * 8;
    size_t g = (size_t)m * OUT_F + c;

    float nm[8] = {};
#pragma unroll
    for (int bk = 0; bk < SPLITK; bk++) {
        u16x8 v = *(const u16x8*)(num + (size_t)bk * N * OUT_F + g);
#pragma unroll
        for (int e = 0; e < 8; e++) nm[e] += __uint_as_float((unsigned)v[e] << 16);
    }
    float l = 0.f;
#pragma unroll
    for (int bk = 0; bk < SPLITK; bk++) l += lpart[(size_t)bk * N + m];
    float inv = 1.f / fmaxf(l, 1e-30f);

    float4 r0 = *(const float4*)(rnd + g);
    float4 r1 = *(const float4*)(rnd + g + 4);
    float rv[8] = { r0.x, r0.y, r0.z, r0.w, r1.x, r1.y, r1.z, r1.w };
    float ov[8];
#pragma unroll
    for (int e = 0; e < 8; e++) {
        float x = (nm[e] * inv + rv[e]) * 1e-5f;
        ov[e] = x > 0.f ? x : __expf(x) - 1.f;
    }
    *(float4*)(out + g)     = make_float4(ov[0], ov[1], ov[2], ov[3]);
    *(float4*)(out + g + 4) = make_float4(ov[4], ov[5], ov[6], ov[7]);
}

extern "C" void kernel_launch(void* const* d_in, const int* in_sizes, int n_in,
                              void* d_out, int out_size, void* d_ws, size_t ws_size,
                              hipStream_t stream) {
    const float* h   = (const float*)d_in[0];
    const int*   adj = (const int*)d_in[1];
    const float* W   = (const float*)d_in[2];
    const float* a   = (const float*)d_in[3];
    const float* rnd = (const float*)d_in[4];
    float* out = (float*)d_out;

    char* w = (char*)d_ws;
    short* WT    = (short*)(w);                            // 131072
    short* WhT   = (short*)(w + 131072);                   // 2097152 -> 2228224
    float* sv    = (float*)(w + 2228224);                  // 32768   -> 2260992
    float* tv    = (float*)(w + 2260992);                  // 32768   -> 2293760
    float* lpart = (float*)(w + 2293760);                  // 262144  -> 2555904
    unsigned short* num  = (unsigned short*)(w + 2555904); // 16777216 -> 19333120 (~19 MB)

    prep    <<<256, 256, 0, stream>>>(W, WT);
    gemm_hW <<<512, 256, 0, stream>>>(h, WT, a, WhT, sv, tv);
    attn    <<<1024, 512, 0, stream>>>(adj, WhT, sv, tv, num, lpart);
    finalize<<<512, 256, 0, stream>>>(num, lpart, rnd, out);
}

// Round 10
// 409.011 us; speedup vs baseline: 1.2345x; 1.0853x over previous
//
#include <hip/hip_runtime.h>

#define N 8192
#define IN_F 512
#define OUT_F 128
#define SPLITK 8
#define KC 1024
#define NW (N / 8)
#define LOG2E 1.4426950408889634f
#define LN2 0.6931471805599453f

typedef __attribute__((ext_vector_type(4))) float f32x4;
typedef __attribute__((ext_vector_type(8))) short bf16x8;
typedef __attribute__((ext_vector_type(8))) unsigned short u16x8;
typedef __attribute__((ext_vector_type(4))) int i32x4;

__device__ __forceinline__ short f2bf(float f) {
    union { float f; unsigned u; } c; c.f = f;
    unsigned r = c.u + 0x7FFFu + ((c.u >> 16) & 1u);
    return (short)(r >> 16);
}

__device__ __forceinline__ float exp2fast(float x) {
#if __has_builtin(__builtin_amdgcn_exp2f)
    return __builtin_amdgcn_exp2f(x);
#else
    return __expf(x * LN2);
#endif
}

__device__ __forceinline__ void load_lds16(const void* g, void* l) {
    __builtin_amdgcn_global_load_lds((const __attribute__((address_space(1))) unsigned*)g,
                                     (__attribute__((address_space(3))) unsigned*)l,
                                     16, 0, 0);
}

// ---------------------------------------------------------------- prep: W f32 -> WT bf16 [OUT_F][IN_F]
__global__ __launch_bounds__(256) void prep(const float* __restrict__ W,
                                            short* __restrict__ WT) {
    int idx = blockIdx.x * 256 + threadIdx.x;   // 65536 total
    int n = idx & (OUT_F - 1);
    int k = idx >> 7;
    WT[(size_t)n * IN_F + k] = f2bf(W[idx]);
}

// ---------------------------------------------------------------- gmask: blocks [0,512) gemm-role, [512,2560) mask-role.
// gemm: Wh=h@W -> Bpack (MFMA-fragment-packed) + fused s,t (x LOG2E).
//   Bpack[((G*8+ni)*64 + lane)*8 + e] = bf16(Wh[k][n]), G=k>>5, lane=((k>>3)&3)*16+(n&15), e=k&7, ni=n>>4.
// mask: adj int32 -> row-major bitmask (pure stream, NT loads); overlaps gemm's compute.
__global__ __launch_bounds__(256) void gmask(const float* __restrict__ h,
                                             const short* __restrict__ WT,
                                             const float* __restrict__ a,
                                             const int* __restrict__ adj,
                                             short* __restrict__ Bpack,
                                             float* __restrict__ sOut,
                                             float* __restrict__ tOut,
                                             unsigned char* __restrict__ maskR) {
    if (blockIdx.x >= 512) {
        // ------------------------------ mask role (verbatim r0 mkmask) ------------------------------
        const int wave = threadIdx.x >> 6, lane = threadIdx.x & 63;
        const size_t m = (size_t)(blockIdx.x - 512) * 4 + wave;
        const i32x4* ap = (const i32x4*)(adj + m * N);
        unsigned char* mp = maskR + m * NW;
#pragma unroll 4
        for (int it = 0; it < 16; it++) {
            int b4 = it * 128 + lane * 2;
            i32x4 a0 = __builtin_nontemporal_load(ap + b4);
            i32x4 a1 = __builtin_nontemporal_load(ap + b4 + 1);
            unsigned b = (unsigned)(a0.x > 0) | ((unsigned)(a0.y > 0) << 1) |
                         ((unsigned)(a0.z > 0) << 2) | ((unsigned)(a0.w > 0) << 3) |
                         ((unsigned)(a1.x > 0) << 4) | ((unsigned)(a1.y > 0) << 5) |
                         ((unsigned)(a1.z > 0) << 6) | ((unsigned)(a1.w > 0) << 7);
            mp[it * 64 + lane] = (unsigned char)b;
        }
        return;
    }
    // ------------------------------ gemm role (verbatim r6 gemm_hW) ------------------------------
    const int tid = threadIdx.x;
    const int wave = tid >> 6, lane = tid & 63;
    const int row16 = lane & 15, kgrp = lane >> 4;
    const int m0 = blockIdx.x * 16;
    const int kbase = wave * 128;

    f32x4 acc[8] = {};
    const float4* hp = (const float4*)(h + (size_t)(m0 + row16) * IN_F + kbase);

#pragma unroll
    for (int kk = 0; kk < 128; kk += 32) {
        float4 u0 = hp[kk / 4 + kgrp * 2];
        float4 u1 = hp[kk / 4 + kgrp * 2 + 1];
        bf16x8 af;
        af[0] = f2bf(u0.x); af[1] = f2bf(u0.y); af[2] = f2bf(u0.z); af[3] = f2bf(u0.w);
        af[4] = f2bf(u1.x); af[5] = f2bf(u1.y); af[6] = f2bf(u1.z); af[7] = f2bf(u1.w);
#pragma unroll
        for (int nt = 0; nt < 8; nt++) {
            bf16x8 bf_ = *(const bf16x8*)(WT + (size_t)(nt * 16 + row16) * IN_F + kbase + kk + kgrp * 8);
            acc[nt] = __builtin_amdgcn_mfma_f32_16x16x32_bf16(af, bf_, acc[nt], 0, 0, 0);
        }
    }

    __shared__ float red[4][16][132];
#pragma unroll
    for (int nt = 0; nt < 8; nt++)
#pragma unroll
        for (int r = 0; r < 4; r++)
            red[wave][kgrp * 4 + r][nt * 16 + row16] = acc[nt][r];
    __syncthreads();

    const int row = tid >> 4, seg = tid & 15;
    float v[8];
#pragma unroll
    for (int e = 0; e < 8; e++) {
        int c = seg * 8 + e;
        v[e] = red[0][row][c] + red[1][row][c] + red[2][row][c] + red[3][row][c];
    }
    float sp = 0.f, tp = 0.f;
#pragma unroll
    for (int e = 0; e < 8; e++) {
        sp += v[e] * a[seg * 8 + e];
        tp += v[e] * a[OUT_F + seg * 8 + e];
    }
    sp += __shfl_xor(sp, 1); tp += __shfl_xor(tp, 1);
    sp += __shfl_xor(sp, 2); tp += __shfl_xor(tp, 2);
    sp += __shfl_xor(sp, 4); tp += __shfl_xor(tp, 4);
    sp += __shfl_xor(sp, 8); tp += __shfl_xor(tp, 8);
    if (seg == 0) {
        sOut[m0 + row] = sp * LOG2E;
        tOut[m0 + row] = tp * LOG2E;
    }

    // Bpack scatter: v[e] is Wh[k=m0+row][n=seg*8+e]
    {
        const int k = m0 + row;
        const int G = k >> 5;
        const int ksub = (k >> 3) & 3;
        const int elem = k & 7;
        short* bp = Bpack + ((size_t)(G * 8 + (seg >> 1)) * 64 + ksub * 16 + (seg & 1) * 8) * 8 + elem;
#pragma unroll
        for (int e = 0; e < 8; e++)
            bp[e * 8] = f2bf(v[e]);
    }
}

// ---------------------------------------------------------------- attn: r0 structure (bitmask + LDS-staged B) with Bpack
// fragment layout -> stage is 4x contiguous 1KB global_load_lds per wave, LDS reads are stride-1 (conflict-free).
// 1-D grid 1024; kb = blockIdx.x & 7 XCD-pins the K-slice; 256 thr = 4 waves; wave = 16M x 128N x 1024K.
__global__ __launch_bounds__(256, 4) void attn(const unsigned char* __restrict__ maskR,
                                               const short* __restrict__ Bpack,
                                               const float* __restrict__ s,
                                               const float* __restrict__ t,
                                               unsigned short* __restrict__ num,
                                               float* __restrict__ lpart) {
    const int tid = threadIdx.x;
    const int wave = tid >> 6, lane = tid & 63;
    const int row16 = lane & 15, kgrp = lane >> 4;
    const int kb = blockIdx.x & 7;
    const int mb = blockIdx.x >> 3;
    const int m0 = mb * 64 + wave * 16;
    const int m  = m0 + row16;
    const int ks = kb * KC;

    __shared__ __align__(16) short Bs[2][8192];  // 32 KB: [parity][d*4096 + ni*512 + lane*8]
    __shared__ float tl[KC];                     // 4 KB

    for (int i = tid; i < KC; i += 256) tl[i] = t[ks + i];

    const float s_m = s[m];
    const int4* mp = (const int4*)(maskR + (size_t)m * NW + (ks >> 3));  // 8 int4 = 128 B
    int4 mcur = mp[0], mnxt = mp[1];

    auto stageB = [&](int sup, int par) {
        const short* src = Bpack + (size_t)(kb * 32 + sup * 2) * 4096;
#pragma unroll
        for (int it = 0; it < 4; it++)
            load_lds16(src + it * 2048 + wave * 512 + lane * 8,
                       &Bs[par][it * 2048 + wave * 512]);
    };

    f32x4 acc[8] = {};
    float lsum = 0.f;

    stageB(0, 0);
    __syncthreads();   // tl + B super 0 ready

    for (int sp2 = 0; sp2 < 8; sp2++) {          // mcur = mask int4 #sp2 (2 supersteps)
#pragma unroll
        for (int ss = 0; ss < 2; ss++) {
            const int sp = sp2 * 2 + ss;         // super 0..15
            const int par = ss;                  // == sp & 1
            if (sp + 1 < 16) stageB(sp + 1, par ^ 1);   // async into other parity
#pragma unroll
            for (int d = 0; d < 2; d++) {
                const int g = sp * 2 + d;        // slice 0..31
                const unsigned dw = (unsigned)((const int*)&mcur)[ss * 2 + d];
                const unsigned mbyte = (dw >> (kgrp * 8)) & 0xFFu;

                const float* tp = tl + g * 32 + kgrp * 8;
                float4 tA = *(const float4*)tp;
                float4 tB = *(const float4*)(tp + 4);
                float tv[8] = { tA.x, tA.y, tA.z, tA.w, tB.x, tB.y, tB.z, tB.w };

                bf16x8 bfr[8];
#pragma unroll
                for (int ni = 0; ni < 8; ni++)
                    bfr[ni] = *(const bf16x8*)(&Bs[par][d * 4096 + ni * 512 + lane * 8]);

                unsigned pu[8];
#pragma unroll
                for (int e = 0; e < 8; e++) {
                    float x = s_m + tv[e];
                    x = fmaxf(x, 0.2f * x);                    // leaky relu
                    float p = exp2fast(x);                     // s,t pre-scaled by log2e
                    unsigned u = __float_as_uint(p) & 0xFFFF0000u;
                    u = ((mbyte >> e) & 1u) ? u : 0u;
                    lsum += __uint_as_float(u);                // consistent with numerator
                    pu[e] = u;
                }
                bf16x8 af;
                unsigned* au = (unsigned*)&af;
#pragma unroll
                for (int q = 0; q < 4; q++) au[q] = (pu[2 * q] >> 16) | pu[2 * q + 1];
#pragma unroll
                for (int ni = 0; ni < 8; ni++)
                    acc[ni] = __builtin_amdgcn_mfma_f32_16x16x32_bf16(af, bfr[ni], acc[ni], 0, 0, 0);
            }
            __syncthreads();   // drains stage of sp+1; guards parity reuse
        }
        mcur = mnxt;
        if (sp2 + 2 < 8) mnxt = mp[sp2 + 2];
    }

    // row sum across kgrp lanes
    {
        float v = lsum;
        v += __shfl_xor(v, 16);
        v += __shfl_xor(v, 32);
        if (kgrp == 0) lpart[(size_t)kb * N + m] = v;
    }

    // partial numerator, bf16: C layout row = kgrp*4+r (m within 16), col = ni*16+row16
    unsigned short* np_ = num + ((size_t)kb * N + m0) * OUT_F;
#pragma unroll
    for (int ni = 0; ni < 8; ni++) {
        int n = ni * 16 + row16;
#pragma unroll
        for (int r = 0; r < 4; r++)
            np_[(size_t)(kgrp * 4 + r) * OUT_F + n] = (unsigned short)f2bf(acc[ni][r]);
    }
}

// ---------------------------------------------------------------- finalize: reduce bf16 splits, /l, +rnd, elu
__global__ __launch_bounds__(256) void finalize(const unsigned short* __restrict__ num,
                                                const float* __restrict__ lpart,
                                                const float* __restrict__ rnd,
                                                float* __restrict__ out) {
    int idx = blockIdx.x * 256 + threadIdx.x;   // one thread = 8 outputs
    int m = idx >> 4;
    int c = (idx & 15) * 8;
    size_t g = (size_t)m * OUT_F + c;

    float nm[8] = {};
#pragma unroll
    for (int bk = 0; bk < SPLITK; bk++) {
        u16x8 v = *(const u16x8*)(num + (size_t)bk * N * OUT_F + g);
#pragma unroll
        for (int e = 0; e < 8; e++) nm[e] += __uint_as_float((unsigned)v[e] << 16);
    }
    float l = 0.f;
#pragma unroll
    for (int bk = 0; bk < SPLITK; bk++) l += lpart[(size_t)bk * N + m];
    float inv = 1.f / fmaxf(l, 1e-30f);

    float4 r0 = *(const float4*)(rnd + g);
    float4 r1 = *(const float4*)(rnd + g + 4);
    float rv[8] = { r0.x, r0.y, r0.z, r0.w, r1.x, r1.y, r1.z, r1.w };
    float ov[8];
#pragma unroll
    for (int e = 0; e < 8; e++) {
        float x = (nm[e] * inv + rv[e]) * 1e-5f;
        ov[e] = x > 0.f ? x : __expf(x) - 1.f;
    }
    *(float4*)(out + g)     = make_float4(ov[0], ov[1], ov[2], ov[3]);
    *(float4*)(out + g + 4) = make_float4(ov[4], ov[5], ov[6], ov[7]);
}

extern "C" void kernel_launch(void* const* d_in, const int* in_sizes, int n_in,
                              void* d_out, int out_size, void* d_ws, size_t ws_size,
                              hipStream_t stream) {
    const float* h   = (const float*)d_in[0];
    const int*   adj = (const int*)d_in[1];
    const float* W   = (const float*)d_in[2];
    const float* a   = (const float*)d_in[3];
    const float* rnd = (const float*)d_in[4];
    float* out = (float*)d_out;

    char* w = (char*)d_ws;
    short* WT    = (short*)(w);                            // 131072
    short* Bpack = (short*)(w + 131072);                   // 2097152 -> 2228224
    float* sv    = (float*)(w + 2228224);                  // 32768   -> 2260992
    float* tv    = (float*)(w + 2260992);                  // 32768   -> 2293760
    float* lpart = (float*)(w + 2293760);                  // 262144  -> 2555904
    unsigned short* num  = (unsigned short*)(w + 2555904); // 16777216 -> 19333120
    unsigned char* maskR = (unsigned char*)(w + 19333120); // 8388608  -> 27721728 (~27 MB)

    prep    <<<256, 256, 0, stream>>>(W, WT);
    gmask   <<<2560, 256, 0, stream>>>(h, WT, a, adj, Bpack, sv, tv, maskR);
    attn    <<<1024, 256, 0, stream>>>(maskR, Bpack, sv, tv, num, lpart);
    finalize<<<512, 256, 0, stream>>>(num, lpart, rnd, out);
}